// Round 1
// 233.542 us; speedup vs baseline: 1.0648x; 1.0648x over previous
//
#include <hip/hip_runtime.h>
#include <math.h>

#define NB 1024
#define NF 36
#define ED 256
#define NK 8
#define NN2 1296   // 36*36
#define QPK 162    // 1296/8

typedef _Float16 f16;
typedef f16 f16x8 __attribute__((ext_vector_type(8)));
typedef float f32x4 __attribute__((ext_vector_type(4)));

#define WXSTR 136     // f16 per Wx half-row (128 + 8 pad); 272B = 17*16 (b128-aligned)
#define NFRAG 1536    // 3 row-tiles * 8 kc * 64 lanes, f16x8 each

// ---- ntn_main LDS (dynamic): Xh | Wxh | v  ~= 37.4 KB -> 4 blocks/CU ----
#define XH_OFF  0
#define WXH_OFF 24576                 // 48 * WXSTR * 2 = 13056
#define V_OFF   37632
#define SMEM_MAIN (V_OFF + (72 + 72 + 9) * 4)   // 38244; 4*38244 = 152976 <= 160K

// ---- prep_all LDS layout (dynamic, 64 KiB) ----
#define PXH_OFF 0
#define PXL_OFF 24576
#define PVH_OFF 49152
#define PVL_OFF 57344
#define SMEM_PREP 65536

__device__ __forceinline__ f32x4 mfma16(f16x8 a, f16x8 b, f32x4 c) {
    return __builtin_amdgcn_mfma_f32_16x16x32_f16(a, b, c, 0, 0, 0);
}

// Merged prep: blocks [0,256) pack W -> B-frag order HI ONLY (scaled by 16);
// blocks [256,1280) split X into fragment-order hi/lo and compute v12 via MFMA.
// Wb is folded into the v2 row:  v2'[k,m] = (V2w[k]+Wb[k]).x_m + V2b[k].
__global__ __launch_bounds__(256) void prep_all(
    const float* __restrict__ W, f16x8* __restrict__ WfH,
    const float* __restrict__ texts, f16x8* __restrict__ XfH, f16x8* __restrict__ XfL,
    const float* __restrict__ V1w, const float* __restrict__ V1b,
    const float* __restrict__ V2w, const float* __restrict__ V2b,
    const float* __restrict__ Wb, float* __restrict__ v12)
{
    extern __shared__ char psmem[];
    const int blk = blockIdx.x;
    const int t = threadIdx.x;

    if (blk < 256) {   // ---- W fragment pack (hi only) ----
        int idx = blk * 256 + t;       // 65536 total
        int dox = idx & 31;
        int c   = (idx >> 5) & 255;
        int k   = idx >> 13;
        const float* src = W + ((size_t)(k * 256 + c)) * 256 + dox * 8;
        float4 a = *(const float4*)src;
        float4 b = *(const float4*)(src + 4);
        float v[8] = {a.x, a.y, a.z, a.w, b.x, b.y, b.z, b.w};
        f16x8 hi;
        #pragma unroll
        for (int j = 0; j < 8; ++j) hi[j] = (f16)(v[j] * 16.0f);
        int kc = dox >> 2, qd = dox & 3, ct = c >> 4;
        int fr = ((k * 16 + ct) * 8 + kc) * 64 + qd * 16 + (c & 15);
        WfH[fr] = hi;
        return;
    }

    // ---- X fragment pack + v12 via MFMA ----
    f16x8* XsH = (f16x8*)(psmem + PXH_OFF);
    f16x8* XsL = (f16x8*)(psmem + PXL_OFF);
    f16x8* VfH = (f16x8*)(psmem + PVH_OFF);
    f16x8* VfL = (f16x8*)(psmem + PVL_OFF);
    float* Xraw = (float*)(psmem + PXH_OFF);   // overlay [36][260]; dead before XsH writes

    const int b = blk - 256;
    const float* xb = texts + (size_t)b * NF * ED;

    // V fragments: col = which*8 + k at lane&15; scaled by 16; Wb folded into V2
    #pragma unroll
    for (int i0 = 0; i0 < 2; ++i0) {
        int i = t + i0 * 256;          // [0,512)
        int kc = (i >> 6) & 7, lane = i & 63;
        int q = lane >> 4, col = lane & 15;
        int which = col >> 3, kk = col & 7;
        const float* src  = (which ? V2w : V1w) + kk * 256 + kc * 32 + q * 8;
        const float* srcb = Wb + kk * 256 + kc * 32 + q * 8;
        f16x8 hi, lo;
        #pragma unroll
        for (int j = 0; j < 8; ++j) {
            float sv = src[j] + (which ? srcb[j] : 0.f);
            sv *= 16.0f;
            f16 h = (f16)sv;
            hi[j] = h;
            lo[j] = (f16)(sv - (float)h);
        }
        VfH[i] = hi;
        VfL[i] = lo;
    }

    // Coalesced stage texts -> Xraw (stride 260 floats: 260 % 32 == 4 -> spread banks)
    #pragma unroll
    for (int i0 = 0; i0 < 9; ++i0) {
        int idx = t + i0 * 256;        // [0,2304) float4s
        float4 v = *(const float4*)(xb + (size_t)idx * 4);
        int row = idx >> 6, c4 = idx & 63;
        *(float4*)(Xraw + row * 260 + c4 * 4) = v;
    }
    __syncthreads();

    // Gather fragments to registers (LDS strided reads, conflict-minimal)
    float raw[6][8];
    #pragma unroll
    for (int i0 = 0; i0 < 6; ++i0) {
        int i = t + i0 * 256;          // [0,1536)
        int rt = i >> 9, kc = (i >> 6) & 7, lane = i & 63;
        int q = lane >> 4, l15 = lane & 15;
        int row = rt * 16 + l15;
        if (row < NF) {
            const float* s = Xraw + row * 260 + kc * 32 + q * 8;
            #pragma unroll
            for (int j = 0; j < 8; ++j) raw[i0][j] = s[j];
        } else {
            #pragma unroll
            for (int j = 0; j < 8; ++j) raw[i0][j] = 0.f;
        }
    }
    __syncthreads();   // Xraw reads done; region reused as XsH/XsL

    // Convert + store fragments (LDS + coalesced global)
    #pragma unroll
    for (int i0 = 0; i0 < 6; ++i0) {
        int i = t + i0 * 256;
        f16x8 hi, lo;
        #pragma unroll
        for (int j = 0; j < 8; ++j) {
            float v = raw[i0][j];
            f16 h = (f16)v;
            hi[j] = h;
            lo[j] = (f16)(v - (float)h);
        }
        XsH[i] = hi;
        XsL[i] = lo;
        XfH[(size_t)b * NFRAG + i] = hi;
        XfL[(size_t)b * NFRAG + i] = lo;
    }
    __syncthreads();

    // v12 MFMA: wave w (<3) handles row-tile rt=w
    const int wave = t >> 6, lane = t & 63;
    const int q = lane >> 4, l15 = lane & 15;
    if (wave < 3) {
        f32x4 acc = (f32x4){0.f, 0.f, 0.f, 0.f};
        #pragma unroll
        for (int kc = 0; kc < 8; ++kc) {
            f16x8 ah = XsH[(wave * 8 + kc) * 64 + lane];
            f16x8 al = XsL[(wave * 8 + kc) * 64 + lane];
            f16x8 bh = VfH[kc * 64 + lane];
            f16x8 bl = VfL[kc * 64 + lane];
            acc = mfma16(ah, bh, acc);
            acc = mfma16(ah, bl, acc);
            acc = mfma16(al, bh, acc);
        }
        const int which = l15 >> 3, kk = l15 & 7;
        const float bias = which ? V2b[kk] : V1b[kk];
        #pragma unroll
        for (int r = 0; r < 4; ++r) {
            const int n = wave * 16 + q * 4 + r;
            if (n < NF)
                v12[((size_t)b * 16 + l15) * NF + n] = acc[r] * 0.0625f + bias;
        }
    }
}

// k-pair merged main: one block computes (b, k0=2*kp) and (b, k0+1).
// X-hi LDS reads and X-lo global reads in phase 1 are shared by both k's
// (each X fragment now feeds 4 MFMAs instead of 2); Wxh LDS buffer is
// reused sequentially (store k0 -> phase2 k0 -> store k1 -> phase2 k1).
__global__ __launch_bounds__(256, 4) void ntn_main(
    const f16x8* __restrict__ XfHG, const f16x8* __restrict__ XfLG,
    const f16x8* __restrict__ WfH,
    const float* __restrict__ v12,
    const float* __restrict__ Uw, const float* __restrict__ Ubp,
    float* __restrict__ logits)
{
    extern __shared__ char smem[];
    f16x8* Xh  = (f16x8*)(smem + XH_OFF);
    f16*   Wxh = (f16*)(smem + WXH_OFF);
    float* v1s2 = (float*)(smem + V_OFF);      // [2][36]
    float* v2s2 = v1s2 + 72;                   // [2][36]
    float* Uws  = v1s2 + 144;                  // [9]

    // XCD swizzle: the 4 k-pair blocks of a given b share id&7 (same XCD)
    const int id  = blockIdx.x;
    const int xcd = id & 7;
    const int rem = id >> 3;
    const int kp  = rem & 3;
    const int b   = ((rem >> 2) << 3) | xcd;
    const int k0  = kp * 2;

    const int t    = threadIdx.x;
    const int wave = t >> 6;
    const int lane = t & 63;
    const int quad = lane >> 4;
    const int l15  = lane & 15;

    const f16x8* Xlg = XfLG + (size_t)b * NFRAG;   // X-lo: global (L2/L1-broadcast)

    // ---- stage X-hi fragments into LDS (coalesced dwordx4) ----
    {
        const f16x8* gh = XfHG + (size_t)b * NFRAG;
        #pragma unroll
        for (int i = 0; i < 6; ++i) Xh[t + i * 256] = gh[t + i * 256];
    }
    if (t < 144) {
        const int r = t / 36, n = t - r * 36;
        const int which = r & 1, kq = r >> 1;
        float v = v12[((size_t)b * 16 + which * 8 + (k0 + kq)) * NF + n];
        (which ? v2s2 : v1s2)[kq * 36 + n] = v;
    }
    if (t < 8) Uws[t] = Uw[t];
    if (t == 8) Uws[8] = Ubp[0];
    __syncthreads();

    const f16x8* Wk0 = WfH + (size_t)k0 * 8192;   // 16ct*8kc*64
    const f16x8* Wk1 = Wk0 + 8192;

    f32x4 sacc[2][3];
    #pragma unroll
    for (int kk = 0; kk < 2; ++kk)
        #pragma unroll
        for (int it = 0; it < 3; ++it) sacc[kk][it] = (f32x4){0.f, 0.f, 0.f, 0.f};

    for (int h = 0; h < 2; ++h) {
        // ===== phase 1: Wx[:, half h] for BOTH k's; X loads shared =====
        f32x4 acc[3][2][2];   // [rt][ctslot][kk]
        #pragma unroll
        for (int i = 0; i < 3; ++i)
            #pragma unroll
            for (int j = 0; j < 2; ++j) {
                acc[i][j][0] = (f32x4){0.f, 0.f, 0.f, 0.f};
                acc[i][j][1] = (f32x4){0.f, 0.f, 0.f, 0.f};
            }
        const int ct0 = h * 8 + wave;
        const int ct1 = ct0 + 4;
        #pragma unroll 2
        for (int kc = 0; kc < 8; ++kc) {
            f16x8 w00 = Wk0[(ct0 * 8 + kc) * 64 + lane];
            f16x8 w01 = Wk0[(ct1 * 8 + kc) * 64 + lane];
            f16x8 w10 = Wk1[(ct0 * 8 + kc) * 64 + lane];
            f16x8 w11 = Wk1[(ct1 * 8 + kc) * 64 + lane];
            #pragma unroll
            for (int rt = 0; rt < 3; ++rt) {
                f16x8 ah = Xh[(rt * 8 + kc) * 64 + lane];    // LDS ds_read_b128
                f16x8 al = Xlg[(rt * 8 + kc) * 64 + lane];   // global (L2/L1)
                acc[rt][0][0] = mfma16(ah, w00, acc[rt][0][0]);
                acc[rt][0][0] = mfma16(al, w00, acc[rt][0][0]);
                acc[rt][1][0] = mfma16(ah, w01, acc[rt][1][0]);
                acc[rt][1][0] = mfma16(al, w01, acc[rt][1][0]);
                acc[rt][0][1] = mfma16(ah, w10, acc[rt][0][1]);
                acc[rt][0][1] = mfma16(al, w10, acc[rt][0][1]);
                acc[rt][1][1] = mfma16(ah, w11, acc[rt][1][1]);
                acc[rt][1][1] = mfma16(al, w11, acc[rt][1][1]);
            }
        }
        // ===== per-k sequential: store Wxh -> phase 2 =====
        #pragma unroll
        for (int kk = 0; kk < 2; ++kk) {
            __syncthreads();   // previous Wxh readers done
            // unscale (W was *16); bias folded into v2 -> plain scale only
            #pragma unroll
            for (int rt = 0; rt < 3; ++rt)
                #pragma unroll
                for (int j2 = 0; j2 < 2; ++j2) {
                    const int cl = (j2 ? (wave + 4) : wave) * 16 + l15;
                    #pragma unroll
                    for (int r = 0; r < 4; ++r) {
                        const int row = rt * 16 + quad * 4 + r;
                        Wxh[row * WXSTR + cl] = (f16)(acc[rt][j2][kk][r] * 0.0625f);
                    }
                }
            __syncthreads();
            // phase 2: S_kk += Wxh * (Xh + Xl)^T (9 tiles over 4 waves)
            #pragma unroll
            for (int it = 0; it < 3; ++it) {
                const int p = wave + it * 4;
                if (p < 9) {
                    const int nt = p / 3, mt = p % 3;
                    const f16* wxh_p = Wxh + (nt * 16 + l15) * WXSTR + quad * 8;
                    #pragma unroll
                    for (int kc2 = 0; kc2 < 4; ++kc2) {
                        f16x8 pah = *(const f16x8*)(wxh_p + kc2 * 32);
                        f16x8 pbh = Xh[(mt * 8 + h * 4 + kc2) * 64 + lane];
                        f16x8 pbl = Xlg[(mt * 8 + h * 4 + kc2) * 64 + lane];
                        sacc[kk][it] = mfma16(pah, pbh, sacc[kk][it]);
                        sacc[kk][it] = mfma16(pah, pbl, sacc[kk][it]);
                    }
                }
            }
        }
    }

    // ===== epilogue: T = tanh(S + v1 + v2) for both k -> Ts (overlays Wxh) =====
    __syncthreads();
    float* Ts = (float*)Wxh;   // 2*1296 f32 = 10368 B <= 13056 B
    #pragma unroll
    for (int kk = 0; kk < 2; ++kk)
        #pragma unroll
        for (int it = 0; it < 3; ++it) {
            const int p = wave + it * 4;
            if (p < 9) {
                const int nt = p / 3, mt = p % 3;
                const int m = mt * 16 + l15;
                if (m < NF) {
                    #pragma unroll
                    for (int r = 0; r < 4; ++r) {
                        const int n = nt * 16 + quad * 4 + r;
                        if (n < NF) {
                            float sv = sacc[kk][it][r] + v1s2[kk * 36 + n] + v2s2[kk * 36 + m];
                            float e = __expf(2.f * sv);
                            Ts[kk * NN2 + n * NF + m] = 1.f - 2.f / (e + 1.f);
                        }
                    }
                }
            }
        }
    __syncthreads();
    #pragma unroll
    for (int u0 = 0; u0 < 2; ++u0) {
        const int u = t + u0 * 256;
        if (u < 2 * QPK) {
            const int kk = (u >= QPK);
            const int tt = u - kk * QPK;
            const float* tp = Ts + kk * NN2 + tt * 8;
            float lg = Uws[8];
            #pragma unroll
            for (int j = 0; j < 8; ++j) lg += Uws[j] * tp[j];
            logits[(size_t)b * NN2 + (k0 + kk) * QPK + tt] = lg;
        }
    }
}

// ---- in-place row softmax: 4 rows per 256-thread block (one per wave) ----
__global__ __launch_bounds__(256) void softmax_rows(float* __restrict__ out) {
    int row = blockIdx.x * 4 + (threadIdx.x >> 6);
    int t = threadIdx.x & 63;
    float* p = out + (size_t)row * NF;
    float v = (t < NF) ? p[t] : -INFINITY;
    float mx = v;
    #pragma unroll
    for (int off = 32; off > 0; off >>= 1) mx = fmaxf(mx, __shfl_xor(mx, off));
    float e = (t < NF) ? __expf(v - mx) : 0.f;
    float sm = e;
    #pragma unroll
    for (int off = 32; off > 0; off >>= 1) sm += __shfl_xor(sm, off);
    if (t < NF) p[t] = e / sm;
}

extern "C" void kernel_launch(void* const* d_in, const int* in_sizes, int n_in,
                              void* d_out, int out_size, void* d_ws, size_t ws_size,
                              hipStream_t stream) {
    const float* texts = (const float*)d_in[0];
    const float* W     = (const float*)d_in[1];
    const float* Wb    = (const float*)d_in[2];
    const float* V1w   = (const float*)d_in[3];
    const float* V1b   = (const float*)d_in[4];
    const float* V2w   = (const float*)d_in[5];
    const float* V2b   = (const float*)d_in[6];
    const float* Uw    = (const float*)d_in[7];
    const float* Ub    = (const float*)d_in[8];

    char* ws = (char*)d_ws;
    f16x8* WfH = (f16x8*)ws;                                   //  1 MiB
    f16x8* XfH = (f16x8*)(ws + (1 << 20));                     // 24 MiB
    f16x8* XfL = (f16x8*)(ws + (1 << 20) + (size_t)NB * NFRAG * 16);       // 24 MiB
    float* v12 = (float*)(ws + (1 << 20) + (size_t)2 * NB * NFRAG * 16);   // 2.25 MiB
    float* logits = (float*)d_out;

    hipFuncSetAttribute((const void*)prep_all,
                        hipFuncAttributeMaxDynamicSharedMemorySize, SMEM_PREP);
    hipFuncSetAttribute((const void*)ntn_main,
                        hipFuncAttributeMaxDynamicSharedMemorySize, SMEM_MAIN);

    prep_all<<<256 + NB, 256, SMEM_PREP, stream>>>(W, WfH, texts, XfH, XfL,
                                                   V1w, V1b, V2w, V2b, Wb, v12);
    ntn_main<<<NB * NK / 2, 256, SMEM_MAIN, stream>>>(XfH, XfL, WfH, v12, Uw, Ub, logits);
    softmax_rows<<<NB * NF / 4, 256, 0, stream>>>(logits);
}